// Round 2
// baseline (1431.894 us; speedup 1.0000x reference)
//
#include <hip/hip_runtime.h>

// ---------------- problem constants ----------------
#define DDIM 1024          // model dim (K of gemm1, N of gemm2)
#define FDIM 2752          // ffn dim
#define FP   2816          // F padded to 22*128 (zero-padded weights -> no N/K guards)
#define TTOK 8192          // tokens
#define SH_OFF 17408       // routed list capacity (16384 + 8*128 align pad), 128-aligned
#define NA   25600         // SH_OFF + TTOK total assignment rows (h rows)

typedef unsigned short u16;
typedef short bf16x8 __attribute__((ext_vector_type(8)));
typedef float f32x4 __attribute__((ext_vector_type(4)));

__device__ __forceinline__ u16 f2b(float f) {
  unsigned u = __float_as_uint(f);
  u += 0x7fff + ((u >> 16) & 1);   // round-to-nearest-even
  return (u16)(u >> 16);
}
__device__ __forceinline__ float b2f(u16 u) {
  return __uint_as_float(((unsigned)u) << 16);
}

// async global->LDS, 16B per lane. LDS dest is wave-uniform base + lane*16.
__device__ __forceinline__ void async16(const void* g, void* s) {
  __builtin_amdgcn_global_load_lds((const __attribute__((address_space(1))) void*)g,
                                   (__attribute__((address_space(3))) void*)s, 16, 0, 0);
}

// ctrl layout (ints): [0..7] counts, [8..15] cursors, [16..24] off[9], [25] nrb_routed, [26] nrb_total

// ---------------- router: 1 wave per token ----------------
__global__ void router_kernel(const float* __restrict__ x, const float* __restrict__ rw,
                              const float* __restrict__ rb, int* __restrict__ topk_id,
                              float* __restrict__ topk_w, int* __restrict__ ctrl) {
  const int wv = threadIdx.x >> 6, lane = threadIdx.x & 63;
  const int t = blockIdx.x * 4 + wv;
  const float* xr = x + (size_t)t * DDIM;
  float acc[8];
#pragma unroll
  for (int e = 0; e < 8; e++) acc[e] = 0.f;
  for (int d = lane; d < DDIM; d += 64) {
    float xv = xr[d];
    const float4* w4 = (const float4*)(rw + (size_t)d * 8);
    float4 wa = w4[0], wb = w4[1];
    acc[0] += xv * wa.x; acc[1] += xv * wa.y; acc[2] += xv * wa.z; acc[3] += xv * wa.w;
    acc[4] += xv * wb.x; acc[5] += xv * wb.y; acc[6] += xv * wb.z; acc[7] += xv * wb.w;
  }
#pragma unroll
  for (int e = 0; e < 8; e++)
    for (int o = 32; o > 0; o >>= 1) acc[e] += __shfl_xor(acc[e], o, 64);
  if (lane == 0) {
    float l[8];
#pragma unroll
    for (int e = 0; e < 8; e++) l[e] = acc[e] + rb[e];
    int i1 = 0; float b1 = l[0];
#pragma unroll
    for (int e = 1; e < 8; e++) if (l[e] > b1) { b1 = l[e]; i1 = e; }
    int i2 = -1; float b2 = -3.4e38f;
#pragma unroll
    for (int e = 0; e < 8; e++) if (e != i1 && l[e] > b2) { b2 = l[e]; i2 = e; }
    // renormalized top-2 softmax weights: w1 = sigmoid(l1-l2)
    float w1 = 1.f / (1.f + __expf(b2 - b1));
    topk_id[2 * t] = i1; topk_id[2 * t + 1] = i2;
    topk_w[2 * t] = w1;  topk_w[2 * t + 1] = 1.f - w1;
    atomicAdd(&ctrl[i1], 1); atomicAdd(&ctrl[i2], 1);
  }
}

// ---------------- offsets + row-block map (single thread, ~200 iters) ----------------
__global__ void build_kernel(int* __restrict__ ctrl, int2* __restrict__ bmap) {
  if (threadIdx.x != 0 || blockIdx.x != 0) return;
  int o = 0, nrb = 0;
  for (int e = 0; e < 8; e++) {
    ctrl[16 + e] = o;
    int c = ctrl[e];
    int nb = (c + 127) >> 7;
    for (int i = 0; i < nb; i++) bmap[nrb++] = make_int2(o + i * 128, e);
    o += nb * 128;            // 128-aligned segments; o <= 17400 < SH_OFF
  }
  ctrl[25] = nrb;             // routed blocks (<=135)
  ctrl[16 + 8] = SH_OFF;
  for (int i = 0; i < 64; i++) bmap[nrb++] = make_int2(SH_OFF + i * 128, 8);
  ctrl[26] = nrb;             // total (<=199)
}

// ---------------- scatter token ids into per-expert segments + inverse map ----------------
__global__ void fill_kernel(const int* __restrict__ topk_id, int* __restrict__ ctrl,
                            int* __restrict__ tok, int* __restrict__ rowof) {
  int t = blockIdx.x * 256 + threadIdx.x;
  if (t >= TTOK) return;
#pragma unroll
  for (int k = 0; k < 2; k++) {
    int e = topk_id[2 * t + k];
    int pos = atomicAdd(&ctrl[8 + e], 1);
    int idx = ctrl[16 + e] + pos;
    tok[idx] = t; rowof[2 * t + k] = idx;
  }
  tok[SH_OFF + t] = t;
}

// ---------------- x fp32 -> bf16 ----------------
__global__ void cvt_x(const float* __restrict__ x, u16* __restrict__ xb) {
  size_t i = ((size_t)blockIdx.x * 256 + threadIdx.x) * 4;
  float4 v = *(const float4*)(x + i);
  ushort4 o;
  o.x = f2b(v.x); o.y = f2b(v.y); o.z = f2b(v.z); o.w = f2b(v.w);
  *(ushort4*)(xb + i) = o;
}

// ---------------- transpose+cast: out[c][r] = in[r][c] (0 outside R/C) ----------------
__global__ void transpose_cvt(const float* __restrict__ inE, const float* __restrict__ inSh,
                              u16* __restrict__ out, int R, int C, int Cp, int Rp) {
  const float* in = (blockIdx.z < 8) ? inE + (size_t)blockIdx.z * R * C : inSh;
  u16* o = out + (size_t)blockIdx.z * Cp * Rp;
  __shared__ float tile[64 * 65];
  int r0 = blockIdx.x * 64, c0 = blockIdx.y * 64;
#pragma unroll
  for (int i = 0; i < 16; i++) {
    int idx = threadIdx.x + 256 * i;
    int ri = idx >> 6, ci = idx & 63;
    int r = r0 + ri, c = c0 + ci;
    float v = 0.f;
    if (r < R && c < C) v = in[(size_t)r * C + c];
    tile[ci * 65 + ri] = v;
  }
  __syncthreads();
#pragma unroll
  for (int i = 0; i < 16; i++) {
    int idx = threadIdx.x + 256 * i;
    int co = idx >> 6, ro = idx & 63;
    o[(size_t)(c0 + co) * Rp + (r0 + ro)] = f2b(tile[co * 65 + ro]);
  }
}

// ---------------- GEMM1: h = silu(Xg)*(Xu), grouped by expert ----------------
// LDS layout per 8KB tile buffer: 8 chunks of (16 rows x 32 k); within chunk,
// 16B unit index = kq*16 + row  ->  fragment read = chunk_base + lane*16B (conflict-free).
__global__ __launch_bounds__(256, 2)
void gemm_gateup(const u16* __restrict__ xb, const u16* __restrict__ wg, const u16* __restrict__ wu,
                 const int* __restrict__ ctrl, const int2* __restrict__ bmap,
                 const int* __restrict__ tok, u16* __restrict__ h) {
  if ((int)blockIdx.x >= ctrl[26]) return;
  int2 be = bmap[blockIdx.x];
  const int row0 = be.x, e = be.y;
  const int n0 = blockIdx.y * 128;

  __shared__ u16 sA[2 * 4096];
  __shared__ u16 sBg[2 * 4096];
  __shared__ u16 sBu[2 * 4096];

  const int tid = threadIdx.x;
  const int lane = tid & 63, wv = tid >> 6;
  const int rl = lane & 15;        // row within 16-row chunk
  const int k8 = lane >> 4;        // which 16B k-chunk

  // staging sources (lane-swizzled for conflict-free LDS layout)
  const u16* a0 = xb + (size_t)tok[row0 + wv * 16 + rl] * DDIM + k8 * 8;
  const u16* a1 = xb + (size_t)tok[row0 + 64 + wv * 16 + rl] * DDIM + k8 * 8;
  const u16* g0 = wg + ((size_t)e * FP + n0 + wv * 16 + rl) * DDIM + k8 * 8;
  const u16* g1 = g0 + (size_t)64 * DDIM;
  const u16* u0 = wu + ((size_t)e * FP + n0 + wv * 16 + rl) * DDIM + k8 * 8;
  const u16* u1 = u0 + (size_t)64 * DDIM;

  const int ub0 = wv * 512;                 // chunk wv     (u16 units)
  const int ub1 = 2048 + wv * 512;          // chunk 4+wv
  const int amb = (wv >> 1) * 4, bnb = (wv & 1) * 4;   // fragment chunk bases
  const int mb = (wv >> 1) * 64, nb = (wv & 1) * 64;
  const int fr = lane & 15, kq = lane >> 4;

  f32x4 accg[16], accu[16];
#pragma unroll
  for (int i = 0; i < 16; i++) { accg[i] = (f32x4)(0.0f); accu[i] = (f32x4)(0.0f); }

  // preload buffer 0
  async16(a0, sA + ub0);  async16(a1, sA + ub1);
  async16(g0, sBg + ub0); async16(g1, sBg + ub1);
  async16(u0, sBu + ub0); async16(u1, sBu + ub1);

  for (int kk = 0; kk < DDIM; kk += 32) {
    const int co = ((kk >> 5) & 1) * 4096;
    __syncthreads();                         // buf[cur] ready; prior reads of buf[nxt] done
    if (kk + 32 < DDIM) {
      const int no = co ^ 4096;
      const int o = kk + 32;
      async16(a0 + o, sA + no + ub0);  async16(a1 + o, sA + no + ub1);
      async16(g0 + o, sBg + no + ub0); async16(g1 + o, sBg + no + ub1);
      async16(u0 + o, sBu + no + ub0); async16(u1 + o, sBu + no + ub1);
    }
    bf16x8 af[4], bg[4], bu[4];
#pragma unroll
    for (int i = 0; i < 4; i++) {
      af[i] = *(const bf16x8*)(sA + co + (amb + i) * 512 + lane * 8);
      bg[i] = *(const bf16x8*)(sBg + co + (bnb + i) * 512 + lane * 8);
      bu[i] = *(const bf16x8*)(sBu + co + (bnb + i) * 512 + lane * 8);
    }
#pragma unroll
    for (int mi = 0; mi < 4; mi++)
#pragma unroll
      for (int ni = 0; ni < 4; ni++) {
        accg[mi * 4 + ni] = __builtin_amdgcn_mfma_f32_16x16x32_bf16(af[mi], bg[ni], accg[mi * 4 + ni], 0, 0, 0);
        accu[mi * 4 + ni] = __builtin_amdgcn_mfma_f32_16x16x32_bf16(af[mi], bu[ni], accu[mi * 4 + ni], 0, 0, 0);
      }
  }
  // epilogue: h = silu(g)*u, bf16. C layout: col=lane&15, row=(lane>>4)*4+reg
#pragma unroll
  for (int mi = 0; mi < 4; mi++)
#pragma unroll
    for (int ni = 0; ni < 4; ni++) {
      f32x4 g = accg[mi * 4 + ni], u = accu[mi * 4 + ni];
#pragma unroll
      for (int r = 0; r < 4; r++) {
        float gv = g[r];
        float hv = (gv * u[r]) / (1.0f + __expf(-gv));
        int row = row0 + mb + mi * 16 + kq * 4 + r;
        int col = n0 + nb + ni * 16 + fr;
        h[(size_t)row * FP + col] = f2b(hv);
      }
    }
}

// ---------------- GEMM2: ybuf = h @ down (all 200 row-blocks, no atomics) ----------------
__global__ __launch_bounds__(256, 2)
void gemm_down(const u16* __restrict__ h, const u16* __restrict__ wd,
               const int* __restrict__ ctrl, const int2* __restrict__ bmap,
               u16* __restrict__ ybuf) {
  if ((int)blockIdx.x >= ctrl[26]) return;
  int2 be = bmap[blockIdx.x];
  const int row0 = be.x, e = be.y;
  const int n0 = blockIdx.y * 128;

  __shared__ u16 sA[2 * 4096];
  __shared__ u16 sB[2 * 4096];

  const int tid = threadIdx.x;
  const int lane = tid & 63, wv = tid >> 6;
  const int rl = lane & 15, k8 = lane >> 4;

  const u16* a0 = h + (size_t)(row0 + wv * 16 + rl) * FP + k8 * 8;
  const u16* a1 = a0 + (size_t)64 * FP;
  const u16* b0 = wd + ((size_t)e * DDIM + n0 + wv * 16 + rl) * FP + k8 * 8;
  const u16* b1 = b0 + (size_t)64 * FP;

  const int ub0 = wv * 512, ub1 = 2048 + wv * 512;
  const int amb = (wv >> 1) * 4, bnb = (wv & 1) * 4;
  const int mb = (wv >> 1) * 64, nb = (wv & 1) * 64;
  const int fr = lane & 15, kq = lane >> 4;

  f32x4 acc[16];
#pragma unroll
  for (int i = 0; i < 16; i++) acc[i] = (f32x4)(0.0f);

  async16(a0, sA + ub0); async16(a1, sA + ub1);
  async16(b0, sB + ub0); async16(b1, sB + ub1);

  for (int kk = 0; kk < FP; kk += 32) {
    const int co = ((kk >> 5) & 1) * 4096;
    __syncthreads();
    if (kk + 32 < FP) {
      const int no = co ^ 4096;
      const int o = kk + 32;
      async16(a0 + o, sA + no + ub0); async16(a1 + o, sA + no + ub1);
      async16(b0 + o, sB + no + ub0); async16(b1 + o, sB + no + ub1);
    }
    bf16x8 af[4], bf[4];
#pragma unroll
    for (int i = 0; i < 4; i++) {
      af[i] = *(const bf16x8*)(sA + co + (amb + i) * 512 + lane * 8);
      bf[i] = *(const bf16x8*)(sB + co + (bnb + i) * 512 + lane * 8);
    }
#pragma unroll
    for (int mi = 0; mi < 4; mi++)
#pragma unroll
      for (int ni = 0; ni < 4; ni++)
        acc[mi * 4 + ni] = __builtin_amdgcn_mfma_f32_16x16x32_bf16(af[mi], bf[ni], acc[mi * 4 + ni], 0, 0, 0);
  }

#pragma unroll
  for (int mi = 0; mi < 4; mi++)
#pragma unroll
    for (int r = 0; r < 4; r++) {
      int row = row0 + mb + mi * 16 + kq * 4 + r;
#pragma unroll
      for (int ni = 0; ni < 4; ni++) {
        int col = n0 + nb + ni * 16 + fr;
        ybuf[(size_t)row * DDIM + col] = f2b(acc[mi * 4 + ni][r]);
      }
    }
}

// ---------------- combine: out[t] = ysh[t] + w1*y[r1] + w2*y[r2] ----------------
__global__ void combine_kernel(const u16* __restrict__ ybuf, const int* __restrict__ rowof,
                               const float* __restrict__ tw2, float* __restrict__ out) {
  const int t = blockIdx.x, d4 = threadIdx.x;
  const int r1 = rowof[2 * t], r2 = rowof[2 * t + 1];
  const float w1 = tw2[2 * t], w2 = tw2[2 * t + 1];
  ushort4 a = ((const ushort4*)(ybuf + (size_t)(SH_OFF + t) * DDIM))[d4];
  ushort4 b = ((const ushort4*)(ybuf + (size_t)r1 * DDIM))[d4];
  ushort4 c = ((const ushort4*)(ybuf + (size_t)r2 * DDIM))[d4];
  float4 o;
  o.x = b2f(a.x) + w1 * b2f(b.x) + w2 * b2f(c.x);
  o.y = b2f(a.y) + w1 * b2f(b.y) + w2 * b2f(c.y);
  o.z = b2f(a.z) + w1 * b2f(b.z) + w2 * b2f(c.z);
  o.w = b2f(a.w) + w1 * b2f(b.w) + w2 * b2f(c.w);
  ((float4*)(out + (size_t)t * DDIM))[d4] = o;
}

// ---------------- host ----------------
extern "C" void kernel_launch(void* const* d_in, const int* in_sizes, int n_in,
                              void* d_out, int out_size, void* d_ws, size_t ws_size,
                              hipStream_t stream) {
  const float* x       = (const float*)d_in[0];
  const float* rw      = (const float*)d_in[1];
  const float* rb      = (const float*)d_in[2];
  const float* gate_w  = (const float*)d_in[3];
  const float* up_w    = (const float*)d_in[4];
  const float* down_w  = (const float*)d_in[5];
  const float* sh_gate = (const float*)d_in[6];
  const float* sh_up   = (const float*)d_in[7];
  const float* sh_down = (const float*)d_in[8];
  float* out = (float*)d_out;
  char* ws = (char*)d_ws;

  // ws layout (bytes)
  const size_t O_CTRL = 0;                        // 64 ints
  const size_t O_BMAP = 256;                      // int2[256]
  const size_t O_TID  = 2304;                     // int[T*2]
  const size_t O_TW   = O_TID + (size_t)TTOK * 2 * 4;
  const size_t O_TOK  = O_TW + (size_t)TTOK * 2 * 4;
  const size_t O_ROW  = O_TOK + (size_t)NA * 4;
  const size_t O_ZEND = O_ROW + (size_t)TTOK * 2 * 4;  // everything above zeroed
  const size_t O_XB   = (O_ZEND + 255) & ~(size_t)255;
  const size_t O_WG   = O_XB + (size_t)TTOK * DDIM * 2;
  const size_t O_WU   = O_WG + (size_t)9 * FP * DDIM * 2;
  const size_t O_WD   = O_WU + (size_t)9 * FP * DDIM * 2;
  const size_t O_H    = O_WD + (size_t)9 * DDIM * FP * 2;
  // ybuf [NA][DDIM] bf16 aliases wg+wu (dead after gemm_gateup; rebuilt every launch)

  int*   ctrl  = (int*)(ws + O_CTRL);
  int2*  bmap  = (int2*)(ws + O_BMAP);
  int*   tid_  = (int*)(ws + O_TID);
  float* tw_   = (float*)(ws + O_TW);
  int*   tok   = (int*)(ws + O_TOK);
  int*   rowof = (int*)(ws + O_ROW);
  u16*   xb    = (u16*)(ws + O_XB);
  u16*   wg    = (u16*)(ws + O_WG);
  u16*   wu    = (u16*)(ws + O_WU);
  u16*   wd    = (u16*)(ws + O_WD);
  u16*   h     = (u16*)(ws + O_H);
  u16*   ybuf  = (u16*)(ws + O_WG);

  hipMemsetAsync(ws, 0, O_ZEND, stream);

  cvt_x<<<dim3(TTOK * DDIM / 1024), 256, 0, stream>>>(x, xb);
  // gate/up: in [D][F] -> out [FP][D]
  transpose_cvt<<<dim3(16, 44, 9), 256, 0, stream>>>(gate_w, sh_gate, wg, DDIM, FDIM, FP, DDIM);
  transpose_cvt<<<dim3(16, 44, 9), 256, 0, stream>>>(up_w, sh_up, wu, DDIM, FDIM, FP, DDIM);
  // down: in [F][D] -> out [D][FP]
  transpose_cvt<<<dim3(44, 16, 9), 256, 0, stream>>>(down_w, sh_down, wd, FDIM, DDIM, DDIM, FP);

  router_kernel<<<dim3(TTOK / 4), 256, 0, stream>>>(x, rw, rb, tid_, tw_, ctrl);
  build_kernel<<<dim3(1), 64, 0, stream>>>(ctrl, bmap);
  fill_kernel<<<dim3(TTOK / 256), 256, 0, stream>>>(tid_, ctrl, tok, rowof);

  gemm_gateup<<<dim3(200, FP / 128), 256, 0, stream>>>(xb, wg, wu, ctrl, bmap, tok, h);
  gemm_down<<<dim3(200, DDIM / 128), 256, 0, stream>>>(h, wd, ctrl, bmap, ybuf);
  combine_kernel<<<dim3(TTOK), 256, 0, stream>>>(ybuf, rowof, tw_, out);
}